// Round 2
// baseline (154.611 us; speedup 1.0000x reference)
//
#include <hip/hip_runtime.h>
#include <hip/hip_bf16.h>

typedef __attribute__((ext_vector_type(8))) short bf16x8;
typedef __attribute__((ext_vector_type(4))) float f32x4;
typedef __hip_bfloat16 bf16;

#define NROWS 8192
#define DIN   2048
#define DD    768
#define CCLS  100
#define BTROWS 896   // 768 P rows + 100 muP rows + 28 zero pad

// monotone float->uint key for atomicMax on signed floats
__device__ __forceinline__ unsigned fkey(float f) {
  unsigned b = __float_as_uint(f);
  return (b & 0x80000000u) ? ~b : (b | 0x80000000u);
}
__device__ __forceinline__ float fdecode(unsigned k) {
  unsigned b = (k & 0x80000000u) ? (k ^ 0x80000000u) : ~k;
  return __uint_as_float(b);
}

// ---------------- prep kernels ----------------

// x f32 -> bf16, 8 elems/thread
__global__ void k_convert_x(const float* __restrict__ x, bf16* __restrict__ xb) {
  long i = ((long)blockIdx.x * 256 + threadIdx.x) * 8;
  float4 v0 = *(const float4*)(x + i);
  float4 v1 = *(const float4*)(x + i + 4);
  union { bf16 h[8]; bf16x8 v; } t;
  t.h[0] = __float2bfloat16(v0.x); t.h[1] = __float2bfloat16(v0.y);
  t.h[2] = __float2bfloat16(v0.z); t.h[3] = __float2bfloat16(v0.w);
  t.h[4] = __float2bfloat16(v1.x); t.h[5] = __float2bfloat16(v1.y);
  t.h[6] = __float2bfloat16(v1.z); t.h[7] = __float2bfloat16(v1.w);
  *(bf16x8*)(xb + i) = t.v;
}

// W [2048,768] f32 -> Wt [768,2048] bf16 (tiled transpose)
__global__ void k_transpose_W(const float* __restrict__ W, bf16* __restrict__ Wt) {
  __shared__ float tile[32][33];
  int tx = threadIdx.x & 31;
  int ty = threadIdx.x >> 5;          // 0..7
  int n0 = blockIdx.x * 32;
  int k0 = blockIdx.y * 32;
#pragma unroll
  for (int i = 0; i < 4; ++i)
    tile[ty + 8*i][tx] = W[(long)(k0 + ty + 8*i) * DD + n0 + tx];
  __syncthreads();
#pragma unroll
  for (int i = 0; i < 4; ++i)
    Wt[(long)(n0 + ty + 8*i) * DIN + k0 + tx] = __float2bfloat16(tile[tx][ty + 8*i]);
}

// P f32 -> BT rows [0,768); zero pad rows [868,896); hm pads [100,128) = +1e30
__global__ void k_convert_P(const float* __restrict__ P, bf16* __restrict__ BT,
                            float* __restrict__ halfmPm) {
  int id = blockIdx.x * 256 + threadIdx.x;     // 0 .. 896*768-1
  int r = id / DD;
  if (r < DD)                BT[id] = __float2bfloat16(P[id]);
  else if (r >= DD + CCLS)   BT[id] = __float2bfloat16(0.f);
  if (id >= CCLS && id < 128) halfmPm[id] = 1e30f;
}

// block (c, j): cols [j*256, j*256+256) of muP[c] = mu[c] @ P; partial 0.5*mu.muP -> atomicAdd hm[c]
__global__ __launch_bounds__(256) void k_prep_mu(const float* __restrict__ mu,
                                                 const float* __restrict__ P,
                                                 bf16* __restrict__ BT,
                                                 float* __restrict__ halfmPm) {
  __shared__ float muL[DD];
  __shared__ float red[256];
  const int tid = threadIdx.x;
  const int c = blockIdx.x;
  const int j = blockIdx.y;
  for (int i = tid; i < DD; i += 256) muL[i] = mu[(long)c * DD + i];
  __syncthreads();
  const int col = j * 256 + tid;
  float a = 0.f;
  for (int d = 0; d < DD; ++d) a += muL[d] * P[(long)d * DD + col];
  BT[(long)(DD + c) * DD + col] = __float2bfloat16(a);
  red[tid] = a * muL[col];
  __syncthreads();
  for (int s = 128; s > 0; s >>= 1) {
    if (tid < s) red[tid] += red[tid + s];
    __syncthreads();
  }
  if (tid == 0) atomicAdd(&halfmPm[c], 0.5f * red[0]);
}

// ---------------- GEMM core: BM=128, BN=64, BK=64, 8 waves (512 thr) ----------------
// A [M,K] row-major bf16, B^T [N,K] row-major bf16; staged via global_load_lds w=16.
// LDS: As[128][64], Bs[64][64]. Staging = 24 chunks of 1KB (8 rows), 3 per wave.

template<int LDK>
__device__ __forceinline__ void gemm_tile_mainloop(
    const bf16* __restrict__ A, const bf16* __restrict__ B,
    long rowA0, long rowB0, bf16* As, bf16* Bs, f32x4 acc[2][2])
{
  const int tid  = threadIdx.x;
  const int lane = tid & 63;
  const int w    = tid >> 6;            // 0..7
  const int wrow = w >> 1, wcol = w & 1;
  const int fr = lane & 15, fq = lane >> 4;
  const int sr = lane >> 3;             // staging row within 8-row chunk
  const int sc = (lane & 7) * 8;        // staging col offset (8 bf16 = 16B)

  for (int kt = 0; kt < LDK; kt += 64) {
#pragma unroll
    for (int i = 0; i < 3; ++i) {
      const int c = w * 3 + i;          // wave-uniform chunk id 0..23
      if (c < 16) {                     // A chunk: rows c*8 .. c*8+8
        const bf16* g = A + (rowA0 + c * 8 + sr) * (long)LDK + kt + sc;
        __builtin_amdgcn_global_load_lds(
            (const __attribute__((address_space(1))) unsigned int*)g,
            (__attribute__((address_space(3))) unsigned int*)(As + c * 512), 16, 0, 0);
      } else {                          // B chunk: rows (c-16)*8 ..
        const int cb = c - 16;
        const bf16* g = B + (rowB0 + cb * 8 + sr) * (long)LDK + kt + sc;
        __builtin_amdgcn_global_load_lds(
            (const __attribute__((address_space(1))) unsigned int*)g,
            (__attribute__((address_space(3))) unsigned int*)(Bs + cb * 512), 16, 0, 0);
      }
    }
    __syncthreads();   // compiler drains vmcnt before s_barrier
#pragma unroll
    for (int kk = 0; kk < 64; kk += 32) {
      bf16x8 av[2], bv[2];
#pragma unroll
      for (int m = 0; m < 2; ++m)
        av[m] = *(const bf16x8*)(As + (wrow * 32 + m * 16 + fr) * 64 + kk + fq * 8);
#pragma unroll
      for (int n = 0; n < 2; ++n)
        bv[n] = *(const bf16x8*)(Bs + (wcol * 32 + n * 16 + fr) * 64 + kk + fq * 8);
#pragma unroll
      for (int m = 0; m < 2; ++m)
#pragma unroll
        for (int n = 0; n < 2; ++n)
          acc[m][n] = __builtin_amdgcn_mfma_f32_16x16x32_bf16(av[m], bv[n], acc[m][n], 0, 0, 0);
    }
    __syncthreads();
  }
}

// GEMM1: zb = xb @ Wt^T   [8192,2048]x[768,2048]^T -> bf16 [8192,768]
__global__ __launch_bounds__(512, 6) void k_gemm1(const bf16* __restrict__ xb,
                                                  const bf16* __restrict__ Wt,
                                                  bf16* __restrict__ zb) {
  __shared__ __align__(16) bf16 As[128 * 64];
  __shared__ __align__(16) bf16 Bs[64 * 64];
  f32x4 acc[2][2];
#pragma unroll
  for (int m = 0; m < 2; ++m)
#pragma unroll
    for (int n = 0; n < 2; ++n) acc[m][n] = (f32x4){0.f, 0.f, 0.f, 0.f};
  const long bm = blockIdx.y, bn = blockIdx.x;
  gemm_tile_mainloop<DIN>(xb, Wt, bm * 128, bn * 64, As, Bs, acc);
  const int tid = threadIdx.x, lane = tid & 63, w = tid >> 6;
  const int wrow = w >> 1, wcol = w & 1, fr = lane & 15, fq = lane >> 4;
#pragma unroll
  for (int m = 0; m < 2; ++m)
#pragma unroll
    for (int n = 0; n < 2; ++n)
#pragma unroll
      for (int j = 0; j < 4; ++j) {
        long row = bm * 128 + wrow * 32 + m * 16 + fq * 4 + j;
        long col = bn * 64 + wcol * 32 + n * 16 + fr;
        zb[row * DD + col] = __float2bfloat16(acc[m][n][j]);
      }
}

// GEMM2: out2 = zb @ BT^T, BT = [P | muP | 0] as [896,768].
// bn<12: zP tile -> rowdot with zb -> atomicAdd zPz[row]
// bn 12,13: score tile -> max_c(s - halfmPm[c]) -> atomicMax smax_u[row]
__global__ __launch_bounds__(512, 6) void k_gemm2(const bf16* __restrict__ zb,
                                                  const bf16* __restrict__ BT,
                                                  const float* __restrict__ halfmPm,
                                                  float* __restrict__ zPz,
                                                  unsigned* __restrict__ smax_u) {
  __shared__ __align__(16) bf16 As[128 * 64];
  __shared__ __align__(16) bf16 Bs[64 * 64];
  f32x4 acc[2][2];
#pragma unroll
  for (int m = 0; m < 2; ++m)
#pragma unroll
    for (int n = 0; n < 2; ++n) acc[m][n] = (f32x4){0.f, 0.f, 0.f, 0.f};
  const long bm = blockIdx.y, bn = blockIdx.x;
  gemm_tile_mainloop<DD>(zb, BT, bm * 128, bn * 64, As, Bs, acc);
  const int tid = threadIdx.x, lane = tid & 63, w = tid >> 6;
  const int wrow = w >> 1, wcol = w & 1, fr = lane & 15, fq = lane >> 4;
  const long row0 = bm * 128 + wrow * 32;

  if (bn < 12) {
    float p[2][4];
#pragma unroll
    for (int m = 0; m < 2; ++m)
#pragma unroll
      for (int j = 0; j < 4; ++j) p[m][j] = 0.f;
#pragma unroll
    for (int m = 0; m < 2; ++m)
#pragma unroll
      for (int n = 0; n < 2; ++n)
#pragma unroll
        for (int j = 0; j < 4; ++j) {
          long row = row0 + m * 16 + fq * 4 + j;
          long col = bn * 64 + wcol * 32 + n * 16 + fr;
          p[m][j] += acc[m][n][j] * __bfloat162float(zb[row * DD + col]);
        }
#pragma unroll
    for (int m = 0; m < 2; ++m)
#pragma unroll
      for (int j = 0; j < 4; ++j) {
        float v = p[m][j];
        v += __shfl_xor(v, 1, 64);
        v += __shfl_xor(v, 2, 64);
        v += __shfl_xor(v, 4, 64);
        v += __shfl_xor(v, 8, 64);
        if (fr == 0)
          atomicAdd(&zPz[row0 + m * 16 + fq * 4 + j], v);
      }
  } else {
    const int cbase = (int)(bn - 12) * 64 + wcol * 32;   // class base for this wave
    float hm0 = halfmPm[cbase + fr];
    float hm1 = halfmPm[cbase + 16 + fr];
#pragma unroll
    for (int m = 0; m < 2; ++m)
#pragma unroll
      for (int j = 0; j < 4; ++j) {
        float v = fmaxf(acc[m][0][j] - hm0, acc[m][1][j] - hm1);
        v = fmaxf(v, __shfl_xor(v, 1, 64));
        v = fmaxf(v, __shfl_xor(v, 2, 64));
        v = fmaxf(v, __shfl_xor(v, 4, 64));
        v = fmaxf(v, __shfl_xor(v, 8, 64));
        if (fr == 0)
          atomicMax(&smax_u[row0 + m * 16 + fq * 4 + j], fkey(v));
      }
  }
}

__global__ void k_final(const unsigned* __restrict__ smax_u, const float* __restrict__ zPz,
                        float* __restrict__ out) {
  int i = blockIdx.x * 256 + threadIdx.x;
  if (i < NROWS) out[i] = fdecode(smax_u[i]) - 0.5f * zPz[i];
}

// ---------------- launch ----------------

extern "C" void kernel_launch(void* const* d_in, const int* in_sizes, int n_in,
                              void* d_out, int out_size, void* d_ws, size_t ws_size,
                              hipStream_t stream) {
  const float* x  = (const float*)d_in[0];
  const float* W  = (const float*)d_in[1];
  const float* mu = (const float*)d_in[2];
  const float* P  = (const float*)d_in[3];
  float* out = (float*)d_out;

  char* ws = (char*)d_ws;
  bf16*     xb     = (bf16*)(ws);                       // 33,554,432
  bf16*     Wt     = (bf16*)(ws + 33554432);            //  3,145,728
  bf16*     BT     = (bf16*)(ws + 36700160);            //  1,376,256
  bf16*     zb     = (bf16*)(ws + 38076416);            // 12,582,912
  float*    hm     = (float*)(ws + 50659328);           // 128*4
  float*    zPz    = (float*)(ws + 50659840);           // 8192*4
  unsigned* smax_u = (unsigned*)(ws + 50692608);        // 8192*4

  hipMemsetAsync(zPz, 0, NROWS * sizeof(float), stream);
  hipMemsetAsync(smax_u, 0, NROWS * sizeof(unsigned), stream);
  hipMemsetAsync(hm, 0, 128 * sizeof(float), stream);
  k_convert_x  <<<8192, 256, 0, stream>>>(x, xb);
  k_transpose_W<<<dim3(24, 64), 256, 0, stream>>>(W, Wt);
  k_convert_P  <<<2688, 256, 0, stream>>>(P, BT, hm);
  k_prep_mu    <<<dim3(CCLS, 3), 256, 0, stream>>>(mu, P, BT, hm);
  k_gemm1      <<<dim3(12, 64), 512, 0, stream>>>(xb, Wt, zb);
  k_gemm2      <<<dim3(14, 64), 512, 0, stream>>>(zb, BT, hm, zPz, smax_u);
  k_final      <<<32, 256, 0, stream>>>(smax_u, zPz, out);
}